// Round 14
// baseline (2009.165 us; speedup 1.0000x reference)
//
#include <hip/hip_runtime.h>

// Batched Jacobi diffusion, B=8, 128x128, iters=1000.
// Round 14: TWO blocks per batch (16 blocks). Batch b = blocks {b, b+8}
// (round-robin XCD mapping pairs them on one XCD -> seam traffic in shared
// L2; perf heuristic only, correctness via agent-scope atomics).
// Block h owns 64 rows = 16 waves x 4-row strips; lane owns float2 col pair.
// Stencil: r13 packed form (4 pk ops + 2 DPP per row).
// Seam fix vs r7: seam row is computed and published FIRST in each step and
// consumed at the START of the next step -> ~0.8 iteration of slack hides
// the L2/IC round trip. Relaxed poll + one acquire fence; release-atomic
// flag from lane 0 (vmcnt-drains the whole wave's row store).

#define GH 128
#define GW 128
#define NW 16      // waves per block
#define RPW 4      // rows per wave
#define NT 1024

typedef float v2f __attribute__((ext_vector_type(2)));

__device__ __forceinline__ float dpp_shr1(float old_v, float src) {
    return __int_as_float(__builtin_amdgcn_update_dpp(
        __float_as_int(old_v), __float_as_int(src), 0x138, 0xf, 0xf, false));
}
__device__ __forceinline__ float dpp_shl1(float old_v, float src) {
    return __int_as_float(__builtin_amdgcn_update_dpp(
        __float_as_int(old_v), __float_as_int(src), 0x130, 0xf, 0xf, false));
}

__global__ void __launch_bounds__(NT)
jacobi_flux_kernel(const float* __restrict__ k_all,
                   const int* __restrict__ iters_p,
                   float* __restrict__ out,
                   float* __restrict__ ws)
{
    __shared__ __align__(16) v2f sTop[2][NW][64];   // 16 KB
    __shared__ __align__(16) v2f sBot[2][NW][64];   // 16 KB

    const int b   = blockIdx.x & 7;     // batch
    const int h   = blockIdx.x >> 3;    // half: 0 = rows 0..63, 1 = 64..127
    const int tid = threadIdx.x;
    const int l   = tid & 63;
    const int w   = tid >> 6;
    const int R0  = h * 64 + w * RPW;   // first grid row of my strip
    const int c0  = l * 2;
    const float* kb = k_all + b * GH * GW;
    const int iters = *iters_p;

    // ---- seam exchange buffers (r7 layout, fits proven ws usage) ----
    float*       myBuf = ws + b * 512 + h * 256;        // 2 parity rows of 128
    const float* nbBuf = ws + b * 512 + (1 - h) * 256;
    int* flags  = (int*)(ws + 8 * 512);
    int* myFlag = flags + b * 32 + h * 16;
    int* nbFlag = flags + b * 32 + (1 - h) * 16;
    const bool seamDn = (h == 0 && w == NW - 1);  // my row 63's dn is external
    const bool seamUp = (h == 1 && w == 0);       // my row 64's up is external
    const bool isSeam = seamDn || seamUp;

    const int wUp = (w == 0)      ? 0      : w - 1;
    const int wDn = (w == NW - 1) ? NW - 1 : w + 1;
    const bool gTop = (h == 0 && w == 0);
    const bool gBot = (h == 1 && w == NW - 1);

    // ---- one-time: packed normalized face conductivities (r13 form) ----
    v2f rN[RPW], rS[RPW], cM[RPW], cLR[RPW];
    #pragma unroll
    for (int i = 0; i < RPW; ++i) {
        const int r  = R0 + i;
        const int ru = (r == 0)      ? 0      : r - 1;
        const int rd = (r == GH - 1) ? GH - 1 : r + 1;
        float v[2][4];
        #pragma unroll
        for (int jj = 0; jj < 2; ++jj) {
            const int c  = c0 + jj;
            const int cl = (c == 0)      ? 0      : c - 1;
            const int cr = (c == GW - 1) ? GW - 1 : c + 1;
            float kc = kb[r * GW + c];
            float kn = 0.5f * (kc + kb[ru * GW + c]);
            float ks = 0.5f * (kc + kb[rd * GW + c]);
            float kw = 0.5f * (kc + kb[r * GW + cl]);
            float ke = 0.5f * (kc + kb[r * GW + cr]);
            float inv = 1.0f / (kn + ks + kw + ke);
            v[jj][0] = kn * inv; v[jj][1] = ks * inv;
            v[jj][2] = kw * inv; v[jj][3] = ke * inv;
        }
        rN[i]  = (v2f){v[0][0], v[1][0]};
        rS[i]  = (v2f){v[0][1], v[1][1]};
        cM[i]  = (v2f){v[0][3], v[1][2]};   // (cE.x, cW.y) pairs with cc.yx
        cLR[i] = (v2f){v[0][2], v[1][3]};   // (cW.x, cE.y) pairs with (lfv,rtv)
    }

    // ---- state ----
    v2f A[RPW], B[RPW];
    #pragma unroll
    for (int i = 0; i < RPW; ++i)
        A[i] = (R0 + i == 0) ? (v2f){1.0f, 1.0f} : (v2f){0.0f, 0.0f};

    sTop[0][w][l] = A[0];
    sBot[0][w][l] = A[RPW - 1];
    __syncthreads();

    auto applyRow = [&](const v2f (&src)[RPW], v2f (&dst)[RPW],
                        int i, v2f up, v2f dn) {
        v2f cc = src[i];
        v2f s;
        s.x = dpp_shr1(cc.x, cc.y);   // left neighbor (grid-edge clamp free)
        s.y = dpp_shl1(cc.y, cc.x);   // right neighbor
        dst[i] = __builtin_elementwise_fma(rN[i], up,
                 __builtin_elementwise_fma(rS[i], dn,
                 __builtin_elementwise_fma(cLR[i], s, cM[i] * cc.yx)));
    };

    auto step = [&](const v2f (&src)[RPW], v2f (&dst)[RPW],
                    int rp, int wp, int it) {
        v2f hu = sBot[rp][wUp][l];   // row R0-1 (garbage for seamUp, unused)
        v2f hd = sTop[rp][wDn][l];   // row R0+RPW (garbage for seamDn, unused)

        if (isSeam) {
            // consume neighbor's state-it seam row (published early last step)
            v2f ext = (v2f){0.0f, 0.0f};          // state 0 seam rows are 0
            if (it > 0) {
                while (__hip_atomic_load(nbFlag, __ATOMIC_RELAXED,
                                         __HIP_MEMORY_SCOPE_AGENT) < it) {}
                __builtin_amdgcn_fence(__ATOMIC_ACQUIRE, "agent");
                ext = *(const v2f*)(nbBuf + (it & 1) * GW + c0);
            }
            // compute + publish the seam row FIRST (max slack for neighbor)
            if (seamDn) applyRow(src, dst, RPW - 1, src[RPW - 2], ext);
            else        applyRow(src, dst, 0,       ext,          src[1]);
            const int sr = seamDn ? (RPW - 1) : 0;
            *(v2f*)(myBuf + ((it + 1) & 1) * GW + c0) = dst[sr];
            if (l == 0)
                __hip_atomic_store(myFlag, it + 1, __ATOMIC_RELEASE,
                                   __HIP_MEMORY_SCOPE_AGENT);
            // remaining rows
            if (seamDn) {
                applyRow(src, dst, 0, hu, src[1]);
                #pragma unroll
                for (int i = 1; i < RPW - 1; ++i)
                    applyRow(src, dst, i, src[i - 1], src[i + 1]);
            } else {
                #pragma unroll
                for (int i = 1; i < RPW - 1; ++i)
                    applyRow(src, dst, i, src[i - 1], src[i + 1]);
                applyRow(src, dst, RPW - 1, src[RPW - 2], hd);
            }
        } else {
            applyRow(src, dst, 0, hu, src[1]);
            #pragma unroll
            for (int i = 1; i < RPW - 1; ++i)
                applyRow(src, dst, i, src[i - 1], src[i + 1]);
            applyRow(src, dst, RPW - 1, src[RPW - 2], hd);
        }

        if (gTop) dst[0]       = (v2f){1.0f, 1.0f};   // Dirichlet row 0
        if (gBot) dst[RPW - 1] = (v2f){0.0f, 0.0f};   // Dirichlet row 127

        sTop[wp][w][l] = dst[0];
        sBot[wp][w][l] = dst[RPW - 1];
        __syncthreads();
    };

    int it = 0;
    const int nPairs = iters >> 1;
    for (int s = 0; s < nPairs; ++s) {
        step(A, B, 0, 1, it); ++it;
        step(B, A, 1, 0, it); ++it;
    }
    if (iters & 1) {
        step(A, B, 0, 1, it);
        #pragma unroll
        for (int i = 0; i < RPW; ++i) A[i] = B[i];
    }

    // ---- flux at row 64: h=1, w=0 holds rows 64..67 (A[0]=r64, A[1]=r65) ----
    if (h == 1 && w == 0) {
        float partial = kb[64 * GW + c0]     * (A[1].x - A[0].x)
                      + kb[64 * GW + c0 + 1] * (A[1].y - A[0].y);
        #pragma unroll
        for (int off = 32; off > 0; off >>= 1)
            partial += __shfl_down(partial, off, 64);
        if (l == 0) out[b] = -partial;
    }
}

extern "C" void kernel_launch(void* const* d_in, const int* in_sizes, int n_in,
                              void* d_out, int out_size, void* d_ws, size_t ws_size,
                              hipStream_t stream)
{
    const float* k     = (const float*)d_in[0];
    const int*   iters = (const int*)d_in[1];
    float*       out   = (float*)d_out;
    float*       ws    = (float*)d_ws;   // ~17.4 KB: seam rows + flags
    jacobi_flux_kernel<<<dim3(16), dim3(NT), 0, stream>>>(k, iters, out, ws);
}